// Round 7
// baseline (140.104 us; speedup 1.0000x reference)
//
#include <hip/hip_runtime.h>
#include <hip/hip_bf16.h>

#define NBH     32          // B*H
#define SEQ     2048
#define DIM     64
#define QBLK    64
#define KBLK    256
#define NCHUNK  (SEQ / KBLK)     // 8
#define PSTR    264              // P row stride in ushorts (528B)

typedef __attribute__((ext_vector_type(4))) float f32x4;
typedef __attribute__((ext_vector_type(8))) short bf16x8;

__device__ __forceinline__ unsigned short bfbits(float f) {
    return __builtin_bit_cast(unsigned short, __float2bfloat16(f));
}

// ---------------------------------------------------------------------------
// V prep: convert V (fp32) into MFMA-B-fragment-ordered bf16 in ws.
// Per 64-row tile tau: ws[bh][tau][ks][dt][lane][j]: element j is
//   V[bh][tau*64 + ks*32 + (lane>>4)*8 + j][dt*16 + (lane&15)]
// ---------------------------------------------------------------------------
__global__ __launch_bounds__(256)
void vprep_kernel(const float* __restrict__ v, unsigned short* __restrict__ wsv)
{
    const int blk = blockIdx.x;            // bh*32 + tau
    const int bh  = blk >> 5, tau = blk & 31;
    const float* vp = v + ((size_t)bh * SEQ + tau * 64) * DIM;
    unsigned short* op = wsv + (size_t)blk * 4096;

    for (int fl = threadIdx.x; fl < 512; fl += 256) {
        const int ks = fl >> 8, dt = (fl >> 6) & 3, lane = fl & 63;
        const int g = lane >> 4, c = lane & 15;
        const float* sp = vp + (ks * 32 + g * 8) * DIM + dt * 16 + c;
        bf16x8 frag;
#pragma unroll
        for (int j = 0; j < 8; ++j)
            frag[j] = (short)bfbits(sp[j * DIM]);
        *reinterpret_cast<bf16x8*>(op + fl * 8) = frag;
    }
}

// ---------------------------------------------------------------------------
// Main kernel: KBLK=256, ONE instruction = ONE contiguous 1KB row-visit
// (lane L reads floats L*4..L*4+3 of a single row). Barrier-free, per-wave
// private P ping-pong, ones-column MFMA computes the softmax denominator.
// Block = 256 threads (4 waves); wave w owns q-rows w*16..w*16+15.
// ---------------------------------------------------------------------------
__global__ __launch_bounds__(256, 2)
void softmaxv_kernel(const float* __restrict__ scores,
                     const unsigned short* __restrict__ vfrags,
                     float* __restrict__ out)
{
    __shared__ unsigned short p_lds[4][2][16 * PSTR];   // 67.6 KB/block

    const int tid  = threadIdx.x;
    const int w    = tid >> 6;
    const int lane = tid & 63;
    const int g    = lane >> 4;       // 0..3
    const int c    = lane & 15;       // 0..15

    const int bid = blockIdx.x;
    const int nb  = (bid & 7) * 128 + (bid >> 3);   // XCD swizzle (1024%8==0, bijective)
    const int bh  = nb >> 5;
    const int qb  = nb & 31;
    const int q0  = qb * QBLK;

    // S: row j of this wave's 16, chunk t -> sp + j*SEQ + t*KBLK (lane gives +lane*4)
    const float* sp = scores + ((size_t)bh * SEQ + q0 + w * 16) * SEQ + lane * 4;
    const unsigned short* vb = vfrags + (size_t)bh * 32 * 4096 + lane * 8;

    unsigned short* pb0 = &p_lds[w][0][0];
    unsigned short* pb1 = &p_lds[w][1][0];

    f32x4 acc[4];
#pragma unroll
    for (int dt = 0; dt < 4; ++dt) acc[dt] = (f32x4)0.0f;
    f32x4 accl = (f32x4)0.0f;                 // row-sum accumulator (ones column)
    bf16x8 ones;
#pragma unroll
    for (int j = 0; j < 8; ++j) ones[j] = (short)0x3F80;   // bf16 1.0

    f32x4 sA[16], sB[16];
    bf16x8 vf[2][4];

#define SLOADS(dst, t)                                                         \
    {                                                                          \
        _Pragma("unroll")                                                      \
        for (int j = 0; j < 16; ++j)                                           \
            dst[j] = *reinterpret_cast<const f32x4*>(                          \
                sp + (size_t)j * SEQ + (t) * KBLK);                            \
    }

#define VLOAD(tau)                                                             \
    {                                                                          \
        _Pragma("unroll")                                                      \
        for (int ks = 0; ks < 2; ++ks)                                         \
            _Pragma("unroll")                                                  \
            for (int dt = 0; dt < 4; ++dt)                                     \
                vf[ks][dt] = *reinterpret_cast<const bf16x8*>(                 \
                    vb + (size_t)(tau) * 4096 + (ks * 4 + dt) * 512);          \
    }

#define HALF(pbuf, half)                                                       \
    {                                                                          \
        _Pragma("unroll")                                                      \
        for (int ks = 0; ks < 2; ++ks) {                                       \
            const bf16x8 a = *reinterpret_cast<const bf16x8*>(                 \
                &pbuf[c * PSTR + (half) * 64 + ks * 32 + g * 8]);              \
            _Pragma("unroll")                                                  \
            for (int dt = 0; dt < 4; ++dt)                                     \
                acc[dt] = __builtin_amdgcn_mfma_f32_16x16x32_bf16(             \
                    a, vf[ks][dt], acc[dt], 0, 0, 0);                          \
            accl = __builtin_amdgcn_mfma_f32_16x16x32_bf16(                    \
                a, ones, accl, 0, 0, 0);                                       \
        }                                                                      \
    }

    // CHUNK: V(first-half) before S-prefetch so HALF0's vmcnt wait doesn't
    // drain the S stream (in-order vmcnt retirement).
#define CHUNK(cur, nxt, t, pbuf, LAST)                                         \
    {                                                                          \
        VLOAD(4 * (t))                                                         \
        if (!(LAST)) SLOADS(nxt, (t) + 1)                                      \
        _Pragma("unroll")                                                      \
        for (int j = 0; j < 16; ++j) {                                         \
            f32x4 s4 = cur[j];                                                 \
            float p0 = __expf(s4[0]);                                          \
            float p1 = __expf(s4[1]);                                          \
            float p2 = __expf(s4[2]);                                          \
            float p3 = __expf(s4[3]);                                          \
            unsigned lo = (unsigned)bfbits(p0) | ((unsigned)bfbits(p1) << 16); \
            unsigned hi = (unsigned)bfbits(p2) | ((unsigned)bfbits(p3) << 16); \
            *reinterpret_cast<uint2*>(&pbuf[j * PSTR + lane * 4]) =            \
                make_uint2(lo, hi);                                            \
        }                                                                      \
        HALF(pbuf, 0)                                                          \
        VLOAD(4 * (t) + 1)                                                     \
        HALF(pbuf, 1)                                                          \
        VLOAD(4 * (t) + 2)                                                     \
        HALF(pbuf, 2)                                                          \
        VLOAD(4 * (t) + 3)                                                     \
        HALF(pbuf, 3)                                                          \
    }

    SLOADS(sA, 0)
    for (int t = 0; t < NCHUNK; t += 2) {
        CHUNK(sA, sB, t, pb0, 0)
        CHUNK(sB, sA, t + 1, pb1, (t + 1 == NCHUNK - 1))
    }
#undef SLOADS
#undef VLOAD
#undef HALF
#undef CHUNK

    // ---- epilogue: denominator is accl (ones-column), no LDS, no shuffles ----
    float rl[4];
#pragma unroll
    for (int r = 0; r < 4; ++r)
        rl[r] = 1.0f / accl[r];

    float* op = out + ((size_t)bh * SEQ + q0 + w * 16) * DIM;
#pragma unroll
    for (int dt = 0; dt < 4; ++dt)
#pragma unroll
        for (int r = 0; r < 4; ++r)
            op[(g * 4 + r) * DIM + dt * 16 + c] = acc[dt][r] * rl[r];
}

extern "C" void kernel_launch(void* const* d_in, const int* in_sizes, int n_in,
                              void* d_out, int out_size, void* d_ws, size_t ws_size,
                              hipStream_t stream)
{
    const float* scores = (const float*)d_in[0];
    const float* v      = (const float*)d_in[1];
    float* out          = (float*)d_out;
    unsigned short* wsv = (unsigned short*)d_ws;   // 8 MB of ws used

    vprep_kernel<<<dim3(NBH * 32), dim3(256), 0, stream>>>(v, wsv);
    softmaxv_kernel<<<dim3(NBH * (SEQ / QBLK)), dim3(256), 0, stream>>>(scores, wsv, out);
}